// Round 8
// baseline (879.785 us; speedup 1.0000x reference)
//
#include <hip/hip_runtime.h>
#include <hip/hip_cooperative_groups.h>

namespace cg = cooperative_groups;

#define N_NODES 200000
#define N_EDGES 800000
#define IN_DIM 768
#define HID 128
#define NG 1024

// MFMA GEMM tile (unchanged from R7)
#define BM 128
#define BKT 32
#define NT (IN_DIM / BKT)     // 24

// scan
#define SCAN_B 1024
#define NSB ((N_NODES + SCAN_B - 1) / SCAN_B)   // 196

// cooperative prep grid
#define PREP_BLOCKS 1024
#define PREP_THREADS (PREP_BLOCKS * 256)

typedef _Float16 f16x8 __attribute__((ext_vector_type(8)));
typedef float f32x4 __attribute__((ext_vector_type(4)));

__device__ __forceinline__ void gload_lds16(const void* g, void* l) {
  __builtin_amdgcn_global_load_lds((const __attribute__((address_space(1))) void*)g,
                                   (__attribute__((address_space(3))) void*)l, 16, 0, 0);
}

__device__ inline void unpack16(unsigned u, float& a, float& b) {
  union { unsigned v; _Float16 f[2]; } c; c.v = u;
  a = (float)c.f[0]; b = (float)c.f[1];
}
__device__ inline unsigned pack16(float a, float b) {
  union { unsigned v; _Float16 f[2]; } c;
  c.f[0] = (_Float16)a; c.f[1] = (_Float16)b;
  return c.v;
}

// ---------------- W_conv -> transposed fp16 (tiny) ----------------
__global__ __launch_bounds__(256) void k_prepW(const float* __restrict__ W,
                                               _Float16* __restrict__ WT) {
  int i = blockIdx.x * 256 + threadIdx.x;
  if (i >= IN_DIM * HID) return;
  int k = i / HID, n = i % HID;
  WT[(size_t)n * IN_DIM + k] = (_Float16)W[i];
}

// ---------------- cooperative prep: zero+deg+scan+dinv+bin in ONE dispatch ----------------
__global__ __launch_bounds__(256) void k_prep(const int* __restrict__ col, const int* __restrict__ row,
                                              int* __restrict__ deg, int* __restrict__ bsum,
                                              int* __restrict__ boff, int* __restrict__ start,
                                              int* __restrict__ cursor, float* __restrict__ dinv,
                                              int2* __restrict__ ew) {
  cg::grid_group grid = cg::this_grid();
  __shared__ int sm[256];
  const int t = threadIdx.x;
  const int gid = blockIdx.x * 256 + t;

  // P0: zero deg
  for (int i = gid; i < N_NODES; i += PREP_THREADS) deg[i] = 0;
  grid.sync();

  // P1: degree atomics
  for (int e = gid; e < N_EDGES; e += PREP_THREADS) atomicAdd(&deg[col[e]], 1);
  grid.sync();

  // P2: per-block partial sums (blocks 0..NSB-1)
  if (blockIdx.x < NSB) {
    int base = blockIdx.x * SCAN_B + t * 4;
    int s = 0;
#pragma unroll
    for (int q = 0; q < 4; ++q) { int idx = base + q; if (idx < N_NODES) s += deg[idx]; }
    sm[t] = s; __syncthreads();
    for (int o = 128; o > 0; o >>= 1) { if (t < o) sm[t] += sm[t + o]; __syncthreads(); }
    if (t == 0) bsum[blockIdx.x] = sm[0];
  }
  grid.sync();

  // P3: scan bsum -> boff (block 0)
  if (blockIdx.x == 0) {
    int v = (t < NSB) ? bsum[t] : 0;
    sm[t] = v; __syncthreads();
    for (int o = 1; o < 256; o <<= 1) {
      int add = (t >= o) ? sm[t - o] : 0;
      __syncthreads();
      sm[t] += add;
      __syncthreads();
    }
    if (t < NSB) boff[t] = sm[t] - v;   // exclusive
  }
  grid.sync();

  // P4: start/cursor/dinv (blocks 0..NSB-1)
  if (blockIdx.x < NSB) {
    int base = blockIdx.x * SCAN_B + t * 4;
    int v[4]; int sum = 0;
#pragma unroll
    for (int q = 0; q < 4; ++q) { v[q] = (base + q < N_NODES) ? deg[base + q] : 0; sum += v[q]; }
    sm[t] = sum; __syncthreads();
    int my = sum;
    for (int o = 1; o < 256; o <<= 1) {
      int add = (t >= o) ? sm[t - o] : 0;
      __syncthreads();
      sm[t] += add;
      __syncthreads();
    }
    int excl = sm[t] - my + boff[blockIdx.x];
#pragma unroll
    for (int q = 0; q < 4; ++q) {
      int idx = base + q;
      if (idx < N_NODES) {
        start[idx] = excl; cursor[idx] = excl; excl += v[q];
        dinv[idx] = rsqrtf((float)(v[q] + 1));   // +1 self loop
      }
    }
    if (blockIdx.x == 0 && t == 0) start[N_NODES] = N_EDGES;
  }
  grid.sync();

  // P5: bin edges into CSR with precomputed weights
  for (int e = gid; e < N_EDGES; e += PREP_THREADS) {
    int r = row[e], c = col[e];
    int slot = atomicAdd(&cursor[c], 1);
    float w = dinv[r] * dinv[c];
    ew[slot] = make_int2(r, __float_as_int(w));
  }
}

// ---------------- h16 = fp16(x @ W_conv) : gload_lds-staged, XOR-swizzled, dbuf (R7) ----------------
__global__ __launch_bounds__(256, 3) void k_gemm_mfma(const float* __restrict__ x,
                                                      const _Float16* __restrict__ WT,
                                                      _Float16* __restrict__ h16) {
  __shared__ __align__(16) char arena[49152];   // 48 KB

  const int t = threadIdx.x;
  const int lane = t & 63;
  const int wid = t >> 6;
  const int bm = blockIdx.x * BM;

  f32x4 acc[2][8];
#pragma unroll
  for (int i = 0; i < 2; ++i)
#pragma unroll
    for (int j = 0; j < 8; ++j) acc[i][j] = (f32x4){0.f, 0.f, 0.f, 0.f};

  const int lr = lane & 15;
  const int s0 = (lane >> 4) * 2;
  const int bslot_r = lane >> 4;

  const int a_srow = lane >> 3;
  const int a_scol = ((lane & 7) ^ (lane >> 3)) * 4;
  const int b_srow = lane >> 2;
  const int b_scol = (((lane & 3) ^ ((lane >> 3) & 3)) * 8);

  auto stage = [&](int k0, int dbuf) {
    char* bA = arena + dbuf * 16384;
    char* bB = arena + 32768 + dbuf * 8192;
#pragma unroll
    for (int p = 0; p < 4; ++p) {
      int r = p * 32 + wid * 8 + a_srow;
      int grow = bm + r; if (grow >= N_NODES) grow = N_NODES - 1;
      gload_lds16(x + (size_t)grow * IN_DIM + k0 + a_scol, bA + p * 4096 + wid * 1024);
    }
#pragma unroll
    for (int p = 0; p < 2; ++p) {
      int r = p * 64 + wid * 16 + b_srow;
      gload_lds16(WT + (size_t)r * IN_DIM + k0 + b_scol, bB + p * 4096 + wid * 1024);
    }
  };

  stage(0, 0);
  __syncthreads();

  for (int tt = 0; tt < NT; ++tt) {
    const int cur = tt & 1;
    if (tt + 1 < NT) stage((tt + 1) * BKT, cur ^ 1);

    const char* bA = arena + cur * 16384;
    const char* bB = arena + 32768 + cur * 8192;

    f16x8 af[2];
#pragma unroll
    for (int rt = 0; rt < 2; ++rt) {
      int r = wid * 32 + rt * 16 + lr;
      const char* rb = bA + r * 128;
      int f = r & 7;
      float4 lo = *(const float4*)(rb + ((s0 ^ f) << 4));
      float4 hi = *(const float4*)(rb + (((s0 + 1) ^ f) << 4));
      af[rt][0] = (_Float16)lo.x; af[rt][1] = (_Float16)lo.y;
      af[rt][2] = (_Float16)lo.z; af[rt][3] = (_Float16)lo.w;
      af[rt][4] = (_Float16)hi.x; af[rt][5] = (_Float16)hi.y;
      af[rt][6] = (_Float16)hi.z; af[rt][7] = (_Float16)hi.w;
    }
#pragma unroll
    for (int ct = 0; ct < 8; ++ct) {
      int cr = ct * 16 + lr;
      f16x8 bf = *(const f16x8*)(bB + cr * 64 + ((bslot_r ^ ((cr >> 1) & 3)) << 4));
      acc[0][ct] = __builtin_amdgcn_mfma_f32_16x16x32_f16(af[0], bf, acc[0][ct], 0, 0, 0);
      acc[1][ct] = __builtin_amdgcn_mfma_f32_16x16x32_f16(af[1], bf, acc[1][ct], 0, 0, 0);
    }
    __syncthreads();
  }

  _Float16* hb = (_Float16*)arena;
  const int dcol = lane & 15;
  const int drow = (lane >> 4) * 4;
#pragma unroll
  for (int rt = 0; rt < 2; ++rt)
#pragma unroll
    for (int j = 0; j < 4; ++j) {
      int rl = wid * 32 + rt * 16 + drow + j;
#pragma unroll
      for (int ct = 0; ct < 8; ++ct)
        hb[rl * HID + ct * 16 + dcol] = (_Float16)acc[rt][ct][j];
    }
  __syncthreads();
#pragma unroll
  for (int q = 0; q < 8; ++q) {
    int f = t + 256 * q;
    int rowl = f >> 4, seg = f & 15;
    int grow = bm + rowl;
    if (grow < N_NODES)
      ((uint4*)(h16 + (size_t)grow * HID))[seg] = ((const uint4*)hb)[f];
  }
}

// ---------------- gather: parallel-edge lane groups, writes per-node conv output ----------------
// wave per 4 nodes; lane = grp(lane>>4) * 16 + fl(lane&15); grp g handles edge c+g;
// each lane accumulates 8 feature-floats (u32 idx fl, fl+16, fl+32, fl+48), then xor-reduce.
__global__ __launch_bounds__(256) void k_gather(const _Float16* __restrict__ h16,
                                                const float* __restrict__ dinv,
                                                const int* __restrict__ start,
                                                const int2* __restrict__ ew,
                                                const float* __restrict__ b_conv,
                                                _Float16* __restrict__ hout16) {
  int gid = blockIdx.x * 256 + threadIdx.x;
  int wv = gid >> 6, lane = gid & 63;
  int n0 = wv * 4;
  if (n0 >= N_NODES) return;
  const int grp = lane >> 4;
  const int fl = lane & 15;
  const int j32 = fl + 16 * grp;                   // this lane's output u32 index
  const unsigned* h32 = (const unsigned*)h16;      // h32[node*64 + u32idx]
  unsigned* ho32 = (unsigned*)hout16;
  const float bc0 = b_conv[2 * j32], bc1 = b_conv[2 * j32 + 1];
  int nend = n0 + 4 < N_NODES ? n0 + 4 : N_NODES;

  for (int i = n0; i < nend; ++i) {
    float acc[8];
#pragma unroll
    for (int q = 0; q < 8; ++q) acc[q] = 0.f;
    int s = start[i], e = start[i + 1];
    for (int c = s; c < e; c += 4) {
      if (c + grp < e) {
        int2 er = ew[c + grp];
        float w = __int_as_float(er.y);
        const unsigned* hr = h32 + (size_t)er.x * 64;
        unsigned u0 = hr[fl];
        unsigned u1 = hr[fl + 16];
        unsigned u2 = hr[fl + 32];
        unsigned u3 = hr[fl + 48];
        float f0, f1;
        unpack16(u0, f0, f1); acc[0] = fmaf(f0, w, acc[0]); acc[1] = fmaf(f1, w, acc[1]);
        unpack16(u1, f0, f1); acc[2] = fmaf(f0, w, acc[2]); acc[3] = fmaf(f1, w, acc[3]);
        unpack16(u2, f0, f1); acc[4] = fmaf(f0, w, acc[4]); acc[5] = fmaf(f1, w, acc[5]);
        unpack16(u3, f0, f1); acc[6] = fmaf(f0, w, acc[6]); acc[7] = fmaf(f1, w, acc[7]);
      }
    }
    // reduce across the 4 lane-groups
#pragma unroll
    for (int q = 0; q < 8; ++q) {
      acc[q] += __shfl_xor(acc[q], 16);
      acc[q] += __shfl_xor(acc[q], 32);
    }
    // pick this lane's pair (static indices only — no runtime array indexing)
    float r0 = acc[0], r1 = acc[1];
    if (grp == 1) { r0 = acc[2]; r1 = acc[3]; }
    else if (grp == 2) { r0 = acc[4]; r1 = acc[5]; }
    else if (grp == 3) { r0 = acc[6]; r1 = acc[7]; }
    // self loop + bias + relu
    float di = dinv[i];
    float sw = di * di;
    float s0, s1;
    unpack16(h32[(size_t)i * 64 + j32], s0, s1);
    float v0 = fmaxf(fmaf(s0, sw, r0) + bc0, 0.f);
    float v1 = fmaxf(fmaf(s1, sw, r1) + bc1, 0.f);
    ho32[(size_t)i * 64 + j32] = pack16(v0, v1);
  }
}

// ---------------- fused head: pool(scan rows) + idx0 + news + hidden + out ----------------
__global__ __launch_bounds__(128) void k_head(const float* __restrict__ x,
                                              const int* __restrict__ batch,
                                              const _Float16* __restrict__ hout16,
                                              const float* __restrict__ W0, const float* __restrict__ b0,
                                              const float* __restrict__ W1, const float* __restrict__ b1,
                                              const float* __restrict__ W2, const float* __restrict__ b2,
                                              float* __restrict__ out) {
  __shared__ float xr[IN_DIM];
  __shared__ float pl[HID];
  __shared__ float nn[HID];
  __shared__ float red[4];
  int g = blockIdx.x, t = threadIdx.x;

  // lo = searchsorted(batch, g), hi = searchsorted(batch, g+1)
  int lo = 0, hi = N_NODES;
  while (lo < hi) { int mid = (lo + hi) >> 1; if (batch[mid] < g) lo = mid + 1; else hi = mid; }
  int lo2 = 0, hi2 = N_NODES;
  int tgt = g + 1;
  while (lo2 < hi2) { int mid = (lo2 + hi2) >> 1; if (batch[mid] < tgt) lo2 = mid + 1; else hi2 = mid; }
  int i0 = lo < N_NODES ? lo : N_NODES - 1;

  // max-pool over this graph's rows (relu'd values >= 0, so init 0 is exact for non-empty)
  const unsigned* ho32 = (const unsigned*)hout16;
  const int u = t >> 1, half = t & 1;
  float m = 0.f;
  int r = lo;
  for (; r + 1 < lo2; r += 2) {
    unsigned a = ho32[(size_t)r * 64 + u];
    unsigned b = ho32[(size_t)(r + 1) * 64 + u];
    float a0, a1, b0v, b1v;
    unpack16(a, a0, a1); unpack16(b, b0v, b1v);
    m = fmaxf(m, half ? a1 : a0);
    m = fmaxf(m, half ? b1v : b0v);
  }
  if (r < lo2) {
    unsigned a = ho32[(size_t)r * 64 + u];
    float a0, a1; unpack16(a, a0, a1);
    m = fmaxf(m, half ? a1 : a0);
  }
  pl[t] = m;

  const float* xp = x + (size_t)i0 * IN_DIM;
  for (int k = t; k < IN_DIM; k += 128) xr[k] = xp[k];
  __syncthreads();

  float a = b0[t];
#pragma unroll 8
  for (int k = 0; k < IN_DIM; ++k) a = fmaf(xr[k], W0[(size_t)k * HID + t], a);
  nn[t] = fmaxf(a, 0.f);
  __syncthreads();

  float z = b1[t];
#pragma unroll 8
  for (int k = 0; k < HID; ++k) z = fmaf(pl[k], W1[(size_t)k * HID + t], z);
#pragma unroll 8
  for (int k = 0; k < HID; ++k) z = fmaf(nn[k], W1[(size_t)(HID + k) * HID + t], z);
  z = fmaxf(z, 0.f);
  float p0 = z * W2[2 * t], p1 = z * W2[2 * t + 1];
#pragma unroll
  for (int o = 32; o > 0; o >>= 1) {
    p0 += __shfl_down(p0, o);
    p1 += __shfl_down(p1, o);
  }
  if ((t & 63) == 0) { red[(t >> 6) * 2] = p0; red[(t >> 6) * 2 + 1] = p1; }
  __syncthreads();
  if (t == 0) {
    float l0 = b2[0] + red[0] + red[2];
    float l1 = b2[1] + red[1] + red[3];
    float mm = fmaxf(l0, l1);
    float lse = mm + logf(expf(l0 - mm) + expf(l1 - mm));
    out[g * 2 + 0] = l0 - lse;
    out[g * 2 + 1] = l1 - lse;
  }
}

extern "C" void kernel_launch(void* const* d_in, const int* in_sizes, int n_in,
                              void* d_out, int out_size, void* d_ws, size_t ws_size,
                              hipStream_t stream) {
  const float* x      = (const float*)d_in[0];
  const int* edge     = (const int*)d_in[1];
  const int* batch    = (const int*)d_in[2];
  const float* W_conv = (const float*)d_in[4];
  const float* b_conv = (const float*)d_in[5];
  const float* W0     = (const float*)d_in[6];
  const float* b0     = (const float*)d_in[7];
  const float* W1     = (const float*)d_in[8];
  const float* b1     = (const float*)d_in[9];
  const float* W2     = (const float*)d_in[10];
  const float* b2     = (const float*)d_in[11];
  float* out = (float*)d_out;

  const int* row = edge;
  const int* col = edge + N_EDGES;

  // workspace layout (bytes); no memsets needed (coop kernel zeroes deg; pool is atomic-free)
  char* ws = (char*)d_ws;
  _Float16*  h16    = (_Float16*)(ws);                   //  51,200,000
  _Float16*  hout16 = (_Float16*)(ws + 51200000);        //  51,200,000
  int*       deg    = (int*)  (ws + 102400000);          //     800,000
  float*     dinv   = (float*)(ws + 103200000);          //     800,000
  int*       start  = (int*)  (ws + 104000000);          //     800,256 (N+1)
  int*       cursor = (int*)  (ws + 104800256);          //     800,000
  int2*      ew     = (int2*) (ws + 105600256);          //   6,400,000
  int*       bsum   = (int*)  (ws + 112000256);          //       1,024
  int*       boff   = (int*)  (ws + 112001280);          //       1,024
  _Float16*  WT     = (_Float16*)(ws + 112002304);       //     196,608

  k_prepW<<<(IN_DIM * HID + 255) / 256, 256, 0, stream>>>(W_conv, WT);
  k_gemm_mfma<<<(N_NODES + BM - 1) / BM, 256, 0, stream>>>(x, WT, h16);

  {
    void* args[] = {(void*)&col, (void*)&row, (void*)&deg, (void*)&bsum, (void*)&boff,
                    (void*)&start, (void*)&cursor, (void*)&dinv, (void*)&ew};
    hipLaunchCooperativeKernel((const void*)k_prep, dim3(PREP_BLOCKS), dim3(256), args, 0, stream);
  }

  k_gather<<<(((N_NODES + 3) / 4) * 64 + 255) / 256, 256, 0, stream>>>(h16, dinv, start, ew, b_conv, hout16);
  k_head<<<NG, 128, 0, stream>>>(x, batch, hout16, W0, b0, W1, b1, W2, b2, out);
}

// Round 9
// 404.063 us; speedup vs baseline: 2.1773x; 2.1773x over previous
//
#include <hip/hip_runtime.h>

#define N_NODES 200000
#define N_EDGES 800000
#define IN_DIM 768
#define HID 128
#define NG 1024

// MFMA GEMM tile
#define BM 128
#define BKT 32
#define NT (IN_DIM / BKT)     // 24

// scan
#define SCAN_B 1024
#define NSB ((N_NODES + SCAN_B - 1) / SCAN_B)   // 196

typedef _Float16 f16x8 __attribute__((ext_vector_type(8)));
typedef float f32x4 __attribute__((ext_vector_type(4)));

__device__ __forceinline__ void gload_lds16(const void* g, void* l) {
  __builtin_amdgcn_global_load_lds((const __attribute__((address_space(1))) void*)g,
                                   (__attribute__((address_space(3))) void*)l, 16, 0, 0);
}

__device__ inline void unpack16(unsigned u, float& a, float& b) {
  union { unsigned v; _Float16 f[2]; } c; c.v = u;
  a = (float)c.f[0]; b = (float)c.f[1];
}
__device__ inline unsigned pack16(float a, float b) {
  union { unsigned v; _Float16 f[2]; } c;
  c.f[0] = (_Float16)a; c.f[1] = (_Float16)b;
  return c.v;
}

// ---------------- degree + W-transpose (independent work, one launch) ----------------
__global__ __launch_bounds__(256) void k_deg_prepW(const int* __restrict__ col, int* __restrict__ deg,
                                                   const float* __restrict__ W, _Float16* __restrict__ WT) {
  int gid = blockIdx.x * 256 + threadIdx.x;
  if (gid < N_EDGES) atomicAdd(&deg[col[gid]], 1);
  if (gid < IN_DIM * HID) {
    int k = gid / HID, n = gid % HID;
    WT[(size_t)n * IN_DIM + k] = (_Float16)W[gid];
  }
}

// ---------------- exclusive scan of deg -> start/cursor (+dinv fused) ----------------
__global__ __launch_bounds__(256) void k_scan1(const int* __restrict__ deg, int* __restrict__ bsum) {
  __shared__ int red[256];
  int b = blockIdx.x, t = threadIdx.x;
  int base = b * SCAN_B + t * 4;
  int s = 0;
#pragma unroll
  for (int q = 0; q < 4; ++q) { int idx = base + q; if (idx < N_NODES) s += deg[idx]; }
  red[t] = s; __syncthreads();
  for (int o = 128; o > 0; o >>= 1) { if (t < o) red[t] += red[t + o]; __syncthreads(); }
  if (t == 0) bsum[b] = red[0];
}

__global__ __launch_bounds__(256) void k_scan2(const int* __restrict__ bsum, int* __restrict__ boff) {
  __shared__ int s[256];
  int t = threadIdx.x;
  int v = (t < NSB) ? bsum[t] : 0;
  s[t] = v; __syncthreads();
  for (int o = 1; o < 256; o <<= 1) {
    int add = (t >= o) ? s[t - o] : 0;
    __syncthreads();
    s[t] += add;
    __syncthreads();
  }
  if (t < NSB) boff[t] = s[t] - v;  // exclusive
}

__global__ __launch_bounds__(256) void k_scan3(const int* __restrict__ deg, const int* __restrict__ boff,
                                               int* __restrict__ start, int* __restrict__ cursor,
                                               float* __restrict__ dinv) {
  __shared__ int s[256];
  int b = blockIdx.x, t = threadIdx.x;
  int base = b * SCAN_B + t * 4;
  int v[4]; int sum = 0;
#pragma unroll
  for (int q = 0; q < 4; ++q) { v[q] = (base + q < N_NODES) ? deg[base + q] : 0; sum += v[q]; }
  s[t] = sum; __syncthreads();
  int my = sum;
  for (int o = 1; o < 256; o <<= 1) {
    int add = (t >= o) ? s[t - o] : 0;
    __syncthreads();
    s[t] += add;
    __syncthreads();
  }
  int excl = s[t] - my + boff[b];
#pragma unroll
  for (int q = 0; q < 4; ++q) {
    int idx = base + q;
    if (idx < N_NODES) {
      start[idx] = excl; cursor[idx] = excl; excl += v[q];
      dinv[idx] = rsqrtf((float)(v[q] + 1));   // +1 self loop
    }
  }
  if (b == 0 && t == 0) start[N_NODES] = N_EDGES;
}

// ---------------- bin edges into CSR with precomputed weights ----------------
__global__ __launch_bounds__(256) void k_bin(const int* __restrict__ row, const int* __restrict__ col,
                                             const float* __restrict__ dinv,
                                             int* __restrict__ cursor, int2* __restrict__ ew) {
  int e = blockIdx.x * 256 + threadIdx.x;
  if (e < N_EDGES) {
    int r = row[e], c = col[e];
    int slot = atomicAdd(&cursor[c], 1);
    float w = dinv[r] * dinv[c];
    ew[slot] = make_int2(r, __float_as_int(w));
  }
}

// ---------------- h16 = fp16(x @ W_conv) : gload_lds-staged, XOR-swizzled, dbuf ----------------
__global__ __launch_bounds__(256, 3) void k_gemm_mfma(const float* __restrict__ x,
                                                      const _Float16* __restrict__ WT,
                                                      _Float16* __restrict__ h16) {
  __shared__ __align__(16) char arena[49152];   // 48 KB

  const int t = threadIdx.x;
  const int lane = t & 63;
  const int wid = t >> 6;
  const int bm = blockIdx.x * BM;

  f32x4 acc[2][8];
#pragma unroll
  for (int i = 0; i < 2; ++i)
#pragma unroll
    for (int j = 0; j < 8; ++j) acc[i][j] = (f32x4){0.f, 0.f, 0.f, 0.f};

  const int lr = lane & 15;
  const int s0 = (lane >> 4) * 2;
  const int bslot_r = lane >> 4;

  const int a_srow = lane >> 3;
  const int a_scol = ((lane & 7) ^ (lane >> 3)) * 4;
  const int b_srow = lane >> 2;
  const int b_scol = (((lane & 3) ^ ((lane >> 3) & 3)) * 8);

  auto stage = [&](int k0, int dbuf) {
    char* bA = arena + dbuf * 16384;
    char* bB = arena + 32768 + dbuf * 8192;
#pragma unroll
    for (int p = 0; p < 4; ++p) {
      int r = p * 32 + wid * 8 + a_srow;
      int grow = bm + r; if (grow >= N_NODES) grow = N_NODES - 1;
      gload_lds16(x + (size_t)grow * IN_DIM + k0 + a_scol, bA + p * 4096 + wid * 1024);
    }
#pragma unroll
    for (int p = 0; p < 2; ++p) {
      int r = p * 64 + wid * 16 + b_srow;
      gload_lds16(WT + (size_t)r * IN_DIM + k0 + b_scol, bB + p * 4096 + wid * 1024);
    }
  };

  stage(0, 0);
  __syncthreads();

  for (int tt = 0; tt < NT; ++tt) {
    const int cur = tt & 1;
    if (tt + 1 < NT) stage((tt + 1) * BKT, cur ^ 1);

    const char* bA = arena + cur * 16384;
    const char* bB = arena + 32768 + cur * 8192;

    f16x8 af[2];
#pragma unroll
    for (int rt = 0; rt < 2; ++rt) {
      int r = wid * 32 + rt * 16 + lr;
      const char* rb = bA + r * 128;
      int f = r & 7;
      float4 lo = *(const float4*)(rb + ((s0 ^ f) << 4));
      float4 hi = *(const float4*)(rb + (((s0 + 1) ^ f) << 4));
      af[rt][0] = (_Float16)lo.x; af[rt][1] = (_Float16)lo.y;
      af[rt][2] = (_Float16)lo.z; af[rt][3] = (_Float16)lo.w;
      af[rt][4] = (_Float16)hi.x; af[rt][5] = (_Float16)hi.y;
      af[rt][6] = (_Float16)hi.z; af[rt][7] = (_Float16)hi.w;
    }
#pragma unroll
    for (int ct = 0; ct < 8; ++ct) {
      int cr = ct * 16 + lr;
      f16x8 bf = *(const f16x8*)(bB + cr * 64 + ((bslot_r ^ ((cr >> 1) & 3)) << 4));
      acc[0][ct] = __builtin_amdgcn_mfma_f32_16x16x32_f16(af[0], bf, acc[0][ct], 0, 0, 0);
      acc[1][ct] = __builtin_amdgcn_mfma_f32_16x16x32_f16(af[1], bf, acc[1][ct], 0, 0, 0);
    }
    __syncthreads();
  }

  _Float16* hb = (_Float16*)arena;
  const int dcol = lane & 15;
  const int drow = (lane >> 4) * 4;
#pragma unroll
  for (int rt = 0; rt < 2; ++rt)
#pragma unroll
    for (int j = 0; j < 4; ++j) {
      int rl = wid * 32 + rt * 16 + drow + j;
#pragma unroll
      for (int ct = 0; ct < 8; ++ct)
        hb[rl * HID + ct * 16 + dcol] = (_Float16)acc[rt][ct][j];
    }
  __syncthreads();
#pragma unroll
  for (int q = 0; q < 8; ++q) {
    int f = t + 256 * q;
    int rowl = f >> 4, seg = f & 15;
    int grow = bm + rowl;
    if (grow < N_NODES)
      ((uint4*)(h16 + (size_t)grow * HID))[seg] = ((const uint4*)hb)[f];
  }
}

// ---------------- gather: parallel-edge lane groups, writes per-node conv output ----------------
__global__ __launch_bounds__(256) void k_gather(const _Float16* __restrict__ h16,
                                                const float* __restrict__ dinv,
                                                const int* __restrict__ start,
                                                const int2* __restrict__ ew,
                                                const float* __restrict__ b_conv,
                                                _Float16* __restrict__ hout16) {
  int gid = blockIdx.x * 256 + threadIdx.x;
  int wv = gid >> 6, lane = gid & 63;
  int n0 = wv * 4;
  if (n0 >= N_NODES) return;
  const int grp = lane >> 4;
  const int fl = lane & 15;
  const int j32 = fl + 16 * grp;
  const unsigned* h32 = (const unsigned*)h16;
  unsigned* ho32 = (unsigned*)hout16;
  const float bc0 = b_conv[2 * j32], bc1 = b_conv[2 * j32 + 1];
  int nend = n0 + 4 < N_NODES ? n0 + 4 : N_NODES;

  for (int i = n0; i < nend; ++i) {
    float acc[8];
#pragma unroll
    for (int q = 0; q < 8; ++q) acc[q] = 0.f;
    int s = start[i], e = start[i + 1];
    for (int c = s; c < e; c += 4) {
      if (c + grp < e) {
        int2 er = ew[c + grp];
        float w = __int_as_float(er.y);
        const unsigned* hr = h32 + (size_t)er.x * 64;
        unsigned u0 = hr[fl];
        unsigned u1 = hr[fl + 16];
        unsigned u2 = hr[fl + 32];
        unsigned u3 = hr[fl + 48];
        float f0, f1;
        unpack16(u0, f0, f1); acc[0] = fmaf(f0, w, acc[0]); acc[1] = fmaf(f1, w, acc[1]);
        unpack16(u1, f0, f1); acc[2] = fmaf(f0, w, acc[2]); acc[3] = fmaf(f1, w, acc[3]);
        unpack16(u2, f0, f1); acc[4] = fmaf(f0, w, acc[4]); acc[5] = fmaf(f1, w, acc[5]);
        unpack16(u3, f0, f1); acc[6] = fmaf(f0, w, acc[6]); acc[7] = fmaf(f1, w, acc[7]);
      }
    }
#pragma unroll
    for (int q = 0; q < 8; ++q) {
      acc[q] += __shfl_xor(acc[q], 16);
      acc[q] += __shfl_xor(acc[q], 32);
    }
    float r0 = acc[0], r1 = acc[1];
    if (grp == 1) { r0 = acc[2]; r1 = acc[3]; }
    else if (grp == 2) { r0 = acc[4]; r1 = acc[5]; }
    else if (grp == 3) { r0 = acc[6]; r1 = acc[7]; }
    float di = dinv[i];
    float sw = di * di;
    float s0, s1;
    unpack16(h32[(size_t)i * 64 + j32], s0, s1);
    float v0 = fmaxf(fmaf(s0, sw, r0) + bc0, 0.f);
    float v1 = fmaxf(fmaf(s1, sw, r1) + bc1, 0.f);
    ho32[(size_t)i * 64 + j32] = pack16(v0, v1);
  }
}

// ---------------- fused head: pool(scan rows) + idx0 + news + hidden + out ----------------
__global__ __launch_bounds__(128) void k_head(const float* __restrict__ x,
                                              const int* __restrict__ batch,
                                              const _Float16* __restrict__ hout16,
                                              const float* __restrict__ W0, const float* __restrict__ b0,
                                              const float* __restrict__ W1, const float* __restrict__ b1,
                                              const float* __restrict__ W2, const float* __restrict__ b2,
                                              float* __restrict__ out) {
  __shared__ float xr[IN_DIM];
  __shared__ float pl[HID];
  __shared__ float nn[HID];
  __shared__ float red[4];
  int g = blockIdx.x, t = threadIdx.x;

  int lo = 0, hi = N_NODES;
  while (lo < hi) { int mid = (lo + hi) >> 1; if (batch[mid] < g) lo = mid + 1; else hi = mid; }
  int lo2 = 0, hi2 = N_NODES;
  int tgt = g + 1;
  while (lo2 < hi2) { int mid = (lo2 + hi2) >> 1; if (batch[mid] < tgt) lo2 = mid + 1; else hi2 = mid; }
  int i0 = lo < N_NODES ? lo : N_NODES - 1;

  const unsigned* ho32 = (const unsigned*)hout16;
  const int u = t >> 1, half = t & 1;
  float m = 0.f;
  int r = lo;
  for (; r + 1 < lo2; r += 2) {
    unsigned a = ho32[(size_t)r * 64 + u];
    unsigned b = ho32[(size_t)(r + 1) * 64 + u];
    float a0, a1, b0v, b1v;
    unpack16(a, a0, a1); unpack16(b, b0v, b1v);
    m = fmaxf(m, half ? a1 : a0);
    m = fmaxf(m, half ? b1v : b0v);
  }
  if (r < lo2) {
    unsigned a = ho32[(size_t)r * 64 + u];
    float a0, a1; unpack16(a, a0, a1);
    m = fmaxf(m, half ? a1 : a0);
  }
  pl[t] = m;

  const float* xp = x + (size_t)i0 * IN_DIM;
  for (int k = t; k < IN_DIM; k += 128) xr[k] = xp[k];
  __syncthreads();

  float a = b0[t];
#pragma unroll 8
  for (int k = 0; k < IN_DIM; ++k) a = fmaf(xr[k], W0[(size_t)k * HID + t], a);
  nn[t] = fmaxf(a, 0.f);
  __syncthreads();

  float z = b1[t];
#pragma unroll 8
  for (int k = 0; k < HID; ++k) z = fmaf(pl[k], W1[(size_t)k * HID + t], z);
#pragma unroll 8
  for (int k = 0; k < HID; ++k) z = fmaf(nn[k], W1[(size_t)(HID + k) * HID + t], z);
  z = fmaxf(z, 0.f);
  float p0 = z * W2[2 * t], p1 = z * W2[2 * t + 1];
#pragma unroll
  for (int o = 32; o > 0; o >>= 1) {
    p0 += __shfl_down(p0, o);
    p1 += __shfl_down(p1, o);
  }
  if ((t & 63) == 0) { red[(t >> 6) * 2] = p0; red[(t >> 6) * 2 + 1] = p1; }
  __syncthreads();
  if (t == 0) {
    float l0 = b2[0] + red[0] + red[2];
    float l1 = b2[1] + red[1] + red[3];
    float mm = fmaxf(l0, l1);
    float lse = mm + logf(expf(l0 - mm) + expf(l1 - mm));
    out[g * 2 + 0] = l0 - lse;
    out[g * 2 + 1] = l1 - lse;
  }
}

extern "C" void kernel_launch(void* const* d_in, const int* in_sizes, int n_in,
                              void* d_out, int out_size, void* d_ws, size_t ws_size,
                              hipStream_t stream) {
  const float* x      = (const float*)d_in[0];
  const int* edge     = (const int*)d_in[1];
  const int* batch    = (const int*)d_in[2];
  const float* W_conv = (const float*)d_in[4];
  const float* b_conv = (const float*)d_in[5];
  const float* W0     = (const float*)d_in[6];
  const float* b0     = (const float*)d_in[7];
  const float* W1     = (const float*)d_in[8];
  const float* b1     = (const float*)d_in[9];
  const float* W2     = (const float*)d_in[10];
  const float* b2     = (const float*)d_in[11];
  float* out = (float*)d_out;

  const int* row = edge;
  const int* col = edge + N_EDGES;

  // workspace layout (bytes)
  char* ws = (char*)d_ws;
  _Float16*  h16    = (_Float16*)(ws);                   //  51,200,000
  _Float16*  hout16 = (_Float16*)(ws + 51200000);        //  51,200,000
  int*       deg    = (int*)  (ws + 102400000);          //     800,000
  float*     dinv   = (float*)(ws + 103200000);          //     800,000
  int*       start  = (int*)  (ws + 104000000);          //     800,256 (N+1)
  int*       cursor = (int*)  (ws + 104800256);          //     800,000
  int2*      ew     = (int2*) (ws + 105600256);          //   6,400,000
  int*       bsum   = (int*)  (ws + 112000256);          //       1,024
  int*       boff   = (int*)  (ws + 112001280);          //       1,024
  _Float16*  WT     = (_Float16*)(ws + 112002304);       //     196,608

  hipMemsetAsync(deg, 0, (size_t)N_NODES * sizeof(int), stream);

  k_deg_prepW<<<(N_EDGES + 255) / 256, 256, 0, stream>>>(col, deg, W_conv, WT);
  k_scan1<<<NSB, 256, 0, stream>>>(deg, bsum);
  k_scan2<<<1, 256, 0, stream>>>(bsum, boff);
  k_scan3<<<NSB, 256, 0, stream>>>(deg, boff, start, cursor, dinv);
  k_bin<<<(N_EDGES + 255) / 256, 256, 0, stream>>>(row, col, dinv, cursor, ew);
  k_gemm_mfma<<<(N_NODES + BM - 1) / BM, 256, 0, stream>>>(x, WT, h16);
  k_gather<<<(((N_NODES + 3) / 4) * 64 + 255) / 256, 256, 0, stream>>>(h16, dinv, start, ew, b_conv, hout16);
  k_head<<<NG, 128, 0, stream>>>(x, batch, hout16, W0, b0, W1, b1, W2, b2, out);
}